// Round 1
// baseline (556.254 us; speedup 1.0000x reference)
//
#include <hip/hip_runtime.h>
#include <cstdint>
#include <cstddef>

// FlowNet-C correlation, MI355X fp32 — round 4: attack the LDS-read-BW bound.
// B=8 C=256 H=64 W=96, PAD=MAXD=20, K=1, S1=1, S2=2 -> 441 output channels.
// out[b, dy*21+dx, y, x] = (1/256) * sum_c in1[b,c,y,x] * in2[b,c,y+2(dy-10), x+2(dx-10)]
//
// R4 design (was: 8x*8dx tile, 0.5 LDS-floats/MAC, ~250-290us of LDS time):
//  - block = one (b,y); 256 thr = 12 x-tiles * 21 dy; grid 512 = 2 blocks/CU.
//  - per-thread tile 8x * 21dx (168 fp32 acc): per channel 48 LDS floats serve
//    168 FMAs -> 0.286 floats/MAC (1.75x less LDS traffic).
//  - in1 read straight from global (L1 broadcast across the 21 dy threads that
//    share each address); LDS holds only in2 rows.
//  - double-buffered in2 staging (CH=2/buf): loads issued before compute,
//    ds_writes after, one barrier per 2 channels.
//  - additive swizzle: row stride 56 f4, +3*(row&7) f4 shift -> read bank-group
//    (3*dy + 2*tx + c) mod 8 ~ balanced 8-9 lanes/group (near the 8-phase floor;
//    linear layout would be 16 phases). All w-reads use one vaddr + imm offsets.

constexpr int B_ = 8, C_ = 256, H_ = 64, W_ = 96;
constexpr int D_ = 21;                 // displacement grid width (per axis)
constexpr int CH = 2;                  // channels staged per buffer
constexpr int TX = 12;                 // x-tiles (8 floats wide) per row
constexpr int THREADS = 256;
constexpr int RS = 56;                 // row stride, float4 units (33+3*7=54 used)
constexpr int JS = D_ * RS;            // channel stride within buffer = 1176 f4
constexpr int BUF = CH * JS;           // f4 per buffer = 2352 (37632 B)
constexpr int NSLOT = CH * D_ * 24;    // interior f4 staging slots = 1008

__global__ __launch_bounds__(THREADS, 2) void corr_fp32(
    const float* __restrict__ in1,
    const float* __restrict__ in2,
    float* __restrict__ out)
{
    __shared__ float4 s2[2 * BUF];     // 75264 B -> 2 blocks/CU

    const int id  = blockIdx.x;
    const int b   = id & 7;            // b fastest -> XCD gets one batch: in2[b]
    const int y   = id >> 3;           //   window L2/L3-resident across its y's
    const int tid = threadIdx.x;

    // ---- compute mapping: thread = (dy, tx) ----
    const int dy = tid / TX;           // 0..20 valid (tid<252)
    const int tx = tid - dy * TX;
    const bool act = (tid < D_ * TX);

    // ---- staging slot descriptors (4 rounds of 256 over 1008 slots) ----
    const float* g2p[4];
    int  l2i[4];
    bool v2b[4];
    #pragma unroll
    for (int it = 0; it < 4; ++it) {
        int slot = tid + it * THREADS;
        bool ok  = slot < NSLOT;
        int sc   = ok ? slot : 0;
        int j    = sc / (D_ * 24);
        int rem  = sc - j * (D_ * 24);
        int r    = rem / 24;
        int u4i  = rem - r * 24;                 // interior chunk 0..23
        int y2   = y + 2 * r - 20;
        ok = ok && (y2 >= 0) && (y2 < H_);
        int y2c  = ok ? y2 : 0;
        g2p[it] = in2 + ((size_t)(b * C_ + j) * H_ + y2c) * W_ + 4 * u4i;
        l2i[it] = (j * D_ + r) * RS + 3 * (r & 7) + (u4i + 5);
        v2b[it] = ok;
    }

    float4 rg[4];
    auto stage_load = [&]() {
        #pragma unroll
        for (int it = 0; it < 4; ++it) {
            if (v2b[it]) rg[it] = *(const float4*)g2p[it];
            g2p[it] += CH * H_ * W_;             // advance CH channels
        }
    };

    // ---- prologue: issue ch{0,1} loads, zero all LDS (pads + OOB rows stay 0
    //      forever: staging only ever rewrites valid interior slots) ----
    stage_load();
    for (int u = tid; u < 2 * BUF; u += THREADS)
        s2[u] = float4{0.f, 0.f, 0.f, 0.f};
    __syncthreads();
    #pragma unroll
    for (int it = 0; it < 4; ++it)
        if (v2b[it]) s2[l2i[it]] = rg[it];       // ch{0,1} -> buf0
    __syncthreads();

    // ---- per-thread compute bases ----
    const int wbase = dy * RS + 3 * (dy & 7) + 2 * tx;   // f4 within buffer
    const float4* pin1 =
        (const float4*)(in1 + ((size_t)(b * C_) * H_ + y) * W_ + 8 * tx);

    float acc[D_][8];
    #pragma unroll
    for (int k = 0; k < D_; ++k)
        #pragma unroll
        for (int i = 0; i < 8; ++i) acc[k][i] = 0.f;

    int rb = 0;
    for (int cc = 0; cc < C_; cc += CH) {
        const bool more = (cc + CH) < C_;
        if (more) stage_load();                  // next 2 channels in flight

        if (act) {
            const float4* wp = &s2[rb + wbase];  // all reads: vaddr + imm offset
            #pragma unroll
            for (int j = 0; j < CH; ++j) {
                float af[8];
                *(float4*)&af[0] = pin1[0];      // in1 via global/L1 (broadcast
                *(float4*)&af[4] = pin1[1];      //  across dy-sharing threads)
                pin1 += (H_ * W_) / 4;
                float wf[48];                    // u = 8tx + f, f = i + 2k
                #pragma unroll
                for (int c = 0; c < 12; ++c)
                    *(float4*)&wf[4 * c] = wp[j * JS + c];
                #pragma unroll
                for (int k = 0; k < D_; ++k)
                    #pragma unroll
                    for (int i = 0; i < 8; ++i)
                        acc[k][i] = fmaf(af[i], wf[2 * k + i], acc[k][i]);
            }
        }

        const int wb = BUF - rb;
        if (more) {
            #pragma unroll
            for (int it = 0; it < 4; ++it)
                if (v2b[it]) s2[wb + l2i[it]] = rg[it];
        }
        __syncthreads();
        rb = wb;                                 // toggle buffers
    }

    // ---- epilogue: 21 dx rows * 8 x, scaled by 1/256 ----
    if (act) {
        const float sc = 1.0f / 256.0f;
        float* po = out + ((size_t)(b * (D_ * D_) + dy * D_) * H_ + y) * W_ + 8 * tx;
        #pragma unroll
        for (int k = 0; k < D_; ++k) {
            float4 v0{acc[k][0] * sc, acc[k][1] * sc, acc[k][2] * sc, acc[k][3] * sc};
            float4 v1{acc[k][4] * sc, acc[k][5] * sc, acc[k][6] * sc, acc[k][7] * sc};
            ((float4*)po)[0] = v0;
            ((float4*)po)[1] = v1;
            po += (size_t)H_ * W_;
        }
    }
}

extern "C" void kernel_launch(void* const* d_in, const int* in_sizes, int n_in,
                              void* d_out, int out_size, void* d_ws, size_t ws_size,
                              hipStream_t stream) {
    const float* in1 = (const float*)d_in[0];
    const float* in2 = (const float*)d_in[1];
    float* out = (float*)d_out;
    (void)in_sizes; (void)n_in; (void)d_ws; (void)ws_size; (void)out_size;
    dim3 grid(B_ * H_);                // 512 blocks: (b fastest, then y)
    corr_fp32<<<grid, dim3(THREADS), 0, stream>>>(in1, in2, out);
}